// Round 5
// baseline (418.280 us; speedup 1.0000x reference)
//
#include <hip/hip_runtime.h>
#include <hip/hip_bf16.h>
#include <stdint.h>

// ---------------------------------------------------------------------------
// CrossViewIPAttnProcessor on MI355X (gfx950)
// B=8, Lq=4096, D=1024, Dc=768, H=16, HD=64, text=77 keys, ip=4 keys
// Round 5: both big GEMMs -> true 8-phase schedule (4 phases/K-tile, BK=64,
// 256x256, 8 waves): per-phase {ds_read subtile; stage 1 half-tile; barrier;
// setprio+16 MFMA; barrier}, single counted vmcnt(6) per tile (3 half-tiles
// in flight). hs pre-converted to bf16 so both GEMMs are pure-bf16 template
// instances. T2 swizzle retained (0 conflicts, R4-verified).
// ---------------------------------------------------------------------------

typedef __attribute__((ext_vector_type(8))) short short8;
typedef __attribute__((ext_vector_type(4))) float f32x4;
typedef __attribute__((ext_vector_type(8))) float float8_t;
typedef __attribute__((ext_vector_type(8))) __bf16 bf16x8;
typedef __attribute__((ext_vector_type(4))) __bf16 bf16x4;

__device__ __forceinline__ ushort f2b(float f) {
  __bf16 h = (__bf16)f;
  return __builtin_bit_cast(ushort, h);
}

__device__ __forceinline__ short8 pack2(float4 a, float4 b) {
  float8_t v;
  v[0] = a.x; v[1] = a.y; v[2] = a.z; v[3] = a.w;
  v[4] = b.x; v[5] = b.y; v[6] = b.z; v[7] = b.w;
  return __builtin_bit_cast(short8, __builtin_convertvector(v, bf16x8));
}

#define GLD16(gp, lp) \
  __builtin_amdgcn_global_load_lds((const __attribute__((address_space(1))) uint32_t*)(gp), \
                                   (__attribute__((address_space(3))) uint32_t*)(lp), 16, 0, 0)

#define FENCE_SCHED() __builtin_amdgcn_sched_barrier(0)

// --------------------- 1) fused fp32 -> bf16 for 6 weights ------------------
struct CvtArgs {
  const float* src[6];
  ushort* dst[6];
  int n4[6];
};

__global__ __launch_bounds__(256) void k_cvt_all(CvtArgs a) {
  int seg = blockIdx.y;
  int i = blockIdx.x * blockDim.x + threadIdx.x;
  if (i >= a.n4[seg]) return;
  float4 v = reinterpret_cast<const float4*>(a.src[seg])[i];
  bf16x4 h;
  h[0] = (__bf16)v.x; h[1] = (__bf16)v.y; h[2] = (__bf16)v.z; h[3] = (__bf16)v.w;
  reinterpret_cast<ushort4*>(a.dst[seg])[i] = __builtin_bit_cast(ushort4, h);
}

// --------------------- 1b) hs fp32 -> bf16 (streaming) ----------------------
__global__ __launch_bounds__(256) void k_cvt_hs(const float* __restrict__ src,
                                                ushort* __restrict__ dst, int n8) {
  int i = blockIdx.x * 256 + threadIdx.x;
  if (i >= n8) return;
  float4 a = reinterpret_cast<const float4*>(src)[i * 2];
  float4 b = reinterpret_cast<const float4*>(src)[i * 2 + 1];
  reinterpret_cast<short8*>(dst)[i] = pack2(a, b);
}

// --------------------------- 2) Xn builder ---------------------------------
__global__ __launch_bounds__(256) void k_build_xn(const float* __restrict__ enc,
                                                  const float* __restrict__ lnw,
                                                  const float* __restrict__ lnb,
                                                  ushort* __restrict__ xn) {
  const int Dc = 768;
  int tok = blockIdx.x, b = blockIdx.y, t = threadIdx.x;
  ushort* out = xn + ((size_t)b * 96 + tok) * Dc;
  bool padrow = (tok >= 84) || (tok >= 77 && tok < 80);
  if (padrow) { out[t] = 0; out[t + 256] = 0; out[t + 512] = 0; return; }
  const float* src = (tok < 77) ? enc + ((size_t)b * 81 + tok) * Dc
                                : enc + ((size_t)b * 81 + 77 + (tok - 80)) * Dc;
  float x0 = src[t], x1 = src[t + 256], x2 = src[t + 512];
  if (tok >= 80) { out[t] = f2b(x0); out[t + 256] = f2b(x1); out[t + 512] = f2b(x2); return; }
  float s = x0 + x1 + x2, q = x0 * x0 + x1 * x1 + x2 * x2;
  for (int m = 32; m; m >>= 1) { s += __shfl_xor(s, m, 64); q += __shfl_xor(q, m, 64); }
  __shared__ float rs[4], rq[4];
  int w = t >> 6;
  if ((t & 63) == 0) { rs[w] = s; rq[w] = q; }
  __syncthreads();
  s = rs[0] + rs[1] + rs[2] + rs[3];
  q = rq[0] + rq[1] + rq[2] + rq[3];
  float mean = s * (1.0f / 768.0f);
  float var = q * (1.0f / 768.0f) - mean * mean;
  float rstd = rsqrtf(var + 1e-5f);
  out[t]       = f2b((x0 - mean) * rstd * lnw[t]       + lnb[t]);
  out[t + 256] = f2b((x1 - mean) * rstd * lnw[t + 256] + lnb[t + 256]);
  out[t + 512] = f2b((x2 - mean) * rstd * lnw[t + 512] + lnb[t + 512]);
}

// --------------------------- 3) K/V projection -----------------------------
__global__ __launch_bounds__(256) void k_kv(const ushort* __restrict__ xn,
                                            const ushort* __restrict__ wb,
                                            const ushort* __restrict__ wipb,
                                            ushort* __restrict__ out, int mode) {
  int n0 = blockIdx.x * 256, b = blockIdx.y;
  int t = threadIdx.x, w = t >> 6, l = t & 63, lo = l & 15, hi = l >> 4;
  __shared__ alignas(16) ushort Xs[96 * 32];
  __shared__ alignas(16) ushort Ws[256 * 32];
  __shared__ alignas(16) ushort Wip[256 * 32];
  f32x4 acc[6][4];
  f32x4 zf = {0.f, 0.f, 0.f, 0.f};
  for (int i = 0; i < 6; i++) for (int j = 0; j < 4; j++) acc[i][j] = zf;
  const ushort* xb = xn + (size_t)b * 96 * 768;
  for (int k0 = 0; k0 < 768; k0 += 32) {
    __syncthreads();
    for (int i = t; i < 96 * 16; i += 256) {
      int row = i >> 4, p = i & 15;
      reinterpret_cast<uint32_t*>(Xs)[i] =
          *reinterpret_cast<const uint32_t*>(xb + row * 768 + k0 + p * 2);
    }
    for (int i = t; i < 256 * 16; i += 256) {
      int row = i >> 4, p = i & 15;
      reinterpret_cast<uint32_t*>(Ws)[i] =
          *reinterpret_cast<const uint32_t*>(wb + (size_t)(n0 + row) * 768 + k0 + p * 2);
      reinterpret_cast<uint32_t*>(Wip)[i] =
          *reinterpret_cast<const uint32_t*>(wipb + (size_t)(n0 + row) * 768 + k0 + p * 2);
    }
    __syncthreads();
    short8 a[6], bb[4], bip[4];
    for (int mi = 0; mi < 6; mi++)
      a[mi] = *reinterpret_cast<const short8*>(Xs + (mi * 16 + lo) * 32 + hi * 8);
    for (int ni = 0; ni < 4; ni++) {
      bb[ni]  = *reinterpret_cast<const short8*>(Ws  + (w * 64 + ni * 16 + lo) * 32 + hi * 8);
      bip[ni] = *reinterpret_cast<const short8*>(Wip + (w * 64 + ni * 16 + lo) * 32 + hi * 8);
    }
    for (int ni = 0; ni < 4; ni++) {
      for (int mi = 0; mi < 5; mi++)
        acc[mi][ni] = __builtin_amdgcn_mfma_f32_16x16x32_bf16(a[mi], bb[ni], acc[mi][ni], 0, 0, 0);
      acc[5][ni] = __builtin_amdgcn_mfma_f32_16x16x32_bf16(a[5], bip[ni], acc[5][ni], 0, 0, 0);
    }
  }
  for (int mi = 0; mi < 6; mi++)
    for (int ni = 0; ni < 4; ni++) {
      int col = n0 + w * 64 + ni * 16 + lo;
      int h = col >> 6, dd = col & 63;
      for (int j = 0; j < 4; j++) {
        int tok = mi * 16 + hi * 4 + j;
        ushort v = f2b(acc[mi][ni][j]);
        if (mode == 0) out[(((size_t)b * 16 + h) * 96 + tok) * 64 + dd] = v;
        else           out[(((size_t)b * 16 + h) * 64 + dd) * 96 + tok] = v;
      }
    }
}

// --------------------- 4/6) 8-phase 256x256 bf16 GEMM ----------------------
// C[32768][1024] = A[32768][1024]bf16 @ Bw[1024][1024]^T bf16 (+bias if BIASED)
// 4 phases per K-tile; per tile staging: A1(t+1)@p0, B0(t+2)@p2,
// B1(t+2)+A0(t+2)@p3, vmcnt(6)@p3 -> 3 half-tiles in flight.
template <bool BIASED>
__global__ __launch_bounds__(512, 2) void k_gemm8(const ushort* __restrict__ A,
                                                  const ushort* __restrict__ Bw,
                                                  const float* __restrict__ bias,
                                                  void* __restrict__ Cv) {
  const int K = 1024, NT = 16;
  int wg = blockIdx.x;
  int nid = (wg & 7) * 64 + (wg >> 3);      // XCD-chunked, nwg=512 (%8==0)
  int m0 = (nid >> 2) * 256, n0 = (nid & 3) * 256;
  int t = threadIdx.x, wid = t >> 6, l = t & 63, lo = l & 15, hi = l >> 4;
  int wr = wid >> 2, wc = wid & 3;
  __shared__ alignas(16) ushort AS[2][256 * 64];
  __shared__ alignas(16) ushort BS[2][256 * 64];
  f32x4 acc[8][4];
  f32x4 zf = {0.f, 0.f, 0.f, 0.f};
#pragma unroll
  for (int i = 0; i < 8; i++)
#pragma unroll
    for (int j = 0; j < 4; j++) acc[i][j] = zf;
  int tr = t >> 3, tc = t & 7;
  int tcs = tc ^ (tr & 7);                  // T2 pre-swizzled source chunk
  const ushort* gA = A  + (size_t)(m0 + tr) * K + tcs * 8;
  const ushort* gB = Bw + (size_t)(n0 + tr) * K + tcs * 8;

#define STG_A(kt_, s_, b_) GLD16(gA + (size_t)(s_) * 64 * K + (kt_) * 64, &AS[b_][(s_) * 4096 + wid * 512])
#define STG_B(kt_, s_, b_) GLD16(gB + (size_t)(s_) * 64 * K + (kt_) * 64, &BS[b_][(s_) * 4096 + wid * 512])

  // ---- prologue: A(0),B(0) then B(1),A0(1); retire first 8, keep 6 ----
  STG_A(0, 0, 0); STG_A(0, 1, 0); STG_A(0, 2, 0); STG_A(0, 3, 0);
  STG_B(0, 0, 0); STG_B(0, 1, 0); STG_B(0, 2, 0); STG_B(0, 3, 0);
  STG_B(1, 0, 1); STG_B(1, 1, 1); STG_B(1, 2, 1); STG_B(1, 3, 1);
  STG_A(1, 0, 1); STG_A(1, 1, 1);
  asm volatile("s_waitcnt vmcnt(6)" ::: "memory");
  __builtin_amdgcn_s_barrier();
  FENCE_SCHED();

  const int swz = (lo & 7) << 3;            // T2 read XOR (ushort units)
  short8 af[4][2], af2[4][2], b01[2][2], b23[2][2];

  for (int kt = 0; kt < NT; kt++) {
    int cur = kt & 1, nxt = cur ^ 1;
    const ushort* sA = &AS[cur][0];
    const ushort* sB = &BS[cur][0];
    // ================= phase 0: af(mi0-3)+b01; MFMA q03 x n01 ==============
#pragma unroll
    for (int q = 0; q < 4; q++)
#pragma unroll
      for (int kk = 0; kk < 2; kk++)
        af[q][kk] = *reinterpret_cast<const short8*>(
            sA + (wr * 128 + q * 16 + lo) * 64 + ((hi * 8 + kk * 32) ^ swz));
#pragma unroll
    for (int n = 0; n < 2; n++)
#pragma unroll
      for (int kk = 0; kk < 2; kk++)
        b01[n][kk] = *reinterpret_cast<const short8*>(
            sB + (wc * 64 + n * 16 + lo) * 64 + ((hi * 8 + kk * 32) ^ swz));
    if (kt + 1 < NT) { STG_A(kt + 1, 2, nxt); STG_A(kt + 1, 3, nxt); }
    __builtin_amdgcn_s_barrier();
    FENCE_SCHED();
    __builtin_amdgcn_s_setprio(1);
#pragma unroll
    for (int q = 0; q < 4; q++)
#pragma unroll
      for (int n = 0; n < 2; n++)
#pragma unroll
        for (int kk = 0; kk < 2; kk++)
          acc[q][n] = __builtin_amdgcn_mfma_f32_16x16x32_bf16(af[q][kk], b01[n][kk], acc[q][n], 0, 0, 0);
    __builtin_amdgcn_s_setprio(0);
    __builtin_amdgcn_s_barrier();
    FENCE_SCHED();
    // ================= phase 1: b23; MFMA q03 x n23 ========================
#pragma unroll
    for (int n = 0; n < 2; n++)
#pragma unroll
      for (int kk = 0; kk < 2; kk++)
        b23[n][kk] = *reinterpret_cast<const short8*>(
            sB + (wc * 64 + (2 + n) * 16 + lo) * 64 + ((hi * 8 + kk * 32) ^ swz));
    __builtin_amdgcn_s_barrier();
    FENCE_SCHED();
    __builtin_amdgcn_s_setprio(1);
#pragma unroll
    for (int q = 0; q < 4; q++)
#pragma unroll
      for (int n = 0; n < 2; n++)
#pragma unroll
        for (int kk = 0; kk < 2; kk++)
          acc[q][2 + n] = __builtin_amdgcn_mfma_f32_16x16x32_bf16(af[q][kk], b23[n][kk], acc[q][2 + n], 0, 0, 0);
    __builtin_amdgcn_s_setprio(0);
    __builtin_amdgcn_s_barrier();
    FENCE_SCHED();
    // ================= phase 2: af2(mi4-7); MFMA q47 x n23 =================
#pragma unroll
    for (int q = 0; q < 4; q++)
#pragma unroll
      for (int kk = 0; kk < 2; kk++)
        af2[q][kk] = *reinterpret_cast<const short8*>(
            sA + (wr * 128 + (4 + q) * 16 + lo) * 64 + ((hi * 8 + kk * 32) ^ swz));
    if (kt + 2 < NT) { STG_B(kt + 2, 0, cur); STG_B(kt + 2, 1, cur); }
    __builtin_amdgcn_s_barrier();
    FENCE_SCHED();
    __builtin_amdgcn_s_setprio(1);
#pragma unroll
    for (int q = 0; q < 4; q++)
#pragma unroll
      for (int n = 0; n < 2; n++)
#pragma unroll
        for (int kk = 0; kk < 2; kk++)
          acc[4 + q][2 + n] = __builtin_amdgcn_mfma_f32_16x16x32_bf16(af2[q][kk], b23[n][kk], acc[4 + q][2 + n], 0, 0, 0);
    __builtin_amdgcn_s_setprio(0);
    __builtin_amdgcn_s_barrier();
    FENCE_SCHED();
    // ================= phase 3: stage B1(t+2)+A0(t+2); vmcnt(6); MFMA q47 x n01
    if (kt + 2 < NT) {
      STG_B(kt + 2, 2, cur); STG_B(kt + 2, 3, cur);
      STG_A(kt + 2, 0, cur); STG_A(kt + 2, 1, cur);
      asm volatile("s_waitcnt vmcnt(6)" ::: "memory");
    } else {
      asm volatile("s_waitcnt vmcnt(0)" ::: "memory");
    }
    __builtin_amdgcn_s_barrier();
    FENCE_SCHED();
    __builtin_amdgcn_s_setprio(1);
#pragma unroll
    for (int q = 0; q < 4; q++)
#pragma unroll
      for (int n = 0; n < 2; n++)
#pragma unroll
        for (int kk = 0; kk < 2; kk++)
          acc[4 + q][n] = __builtin_amdgcn_mfma_f32_16x16x32_bf16(af2[q][kk], b01[n][kk], acc[4 + q][n], 0, 0, 0);
    __builtin_amdgcn_s_setprio(0);
    __builtin_amdgcn_s_barrier();
    FENCE_SCHED();
  }
  // ---- epilogue ----
  if constexpr (BIASED) {
    float* C = (float*)Cv;
#pragma unroll
    for (int n = 0; n < 4; n++) {
      int c = n0 + wc * 64 + n * 16 + lo;
      float bv = bias[c];
#pragma unroll
      for (int mi = 0; mi < 8; mi++)
#pragma unroll
        for (int j = 0; j < 4; j++) {
          int r = m0 + wr * 128 + mi * 16 + hi * 4 + j;
          C[(size_t)r * 1024 + c] = acc[mi][n][j] + bv;
        }
    }
  } else {
    ushort* C = (ushort*)Cv;
#pragma unroll
    for (int mi = 0; mi < 8; mi++)
#pragma unroll
      for (int n = 0; n < 4; n++)
#pragma unroll
        for (int j = 0; j < 4; j++) {
          int r = m0 + wr * 128 + mi * 16 + hi * 4 + j;
          int c = n0 + wc * 64 + n * 16 + lo;
          C[(size_t)r * 1024 + c] = f2b(acc[mi][n][j]);
        }
  }
#undef STG_A
#undef STG_B
}

// --------------------------- 5) attention ----------------------------------
__global__ __launch_bounds__(256) void k_attn(const ushort* __restrict__ Q,
                                              const ushort* __restrict__ Kall,
                                              const ushort* __restrict__ Vt,
                                              ushort* __restrict__ O) {
  int q0 = blockIdx.x * 128, bh = blockIdx.y;
  int b = bh >> 4, h = bh & 15;
  int t = threadIdx.x, w = t >> 6, l = t & 63, lo = l & 15, hi = l >> 4;
  __shared__ alignas(16) ushort P[4][32 * 104];
  const ushort* Qb = Q + ((size_t)b * 4096 + q0 + w * 32) * 1024 + h * 64;
  short8 qf[2][2];
  for (int mi = 0; mi < 2; mi++)
    for (int ks = 0; ks < 2; ks++)
      qf[mi][ks] = *reinterpret_cast<const short8*>(Qb + (size_t)(mi * 16 + lo) * 1024 + ks * 32 + hi * 8);
  const ushort* Kb = Kall + (size_t)bh * 96 * 64;
  f32x4 s[2][6];
  f32x4 zf = {0.f, 0.f, 0.f, 0.f};
  for (int i = 0; i < 2; i++) for (int j = 0; j < 6; j++) s[i][j] = zf;
  for (int ni = 0; ni < 6; ni++)
    for (int ks = 0; ks < 2; ks++) {
      short8 kf = *reinterpret_cast<const short8*>(Kb + (ni * 16 + lo) * 64 + ks * 32 + hi * 8);
      for (int mi = 0; mi < 2; mi++)
        s[mi][ni] = __builtin_amdgcn_mfma_f32_16x16x32_bf16(qf[mi][ks], kf, s[mi][ni], 0, 0, 0);
    }
  const float SC = 0.125f * 1.44269504088896340736f;
  for (int mi = 0; mi < 2; mi++)
    for (int j = 0; j < 4; j++) {
      float pb[5];
      float mb = -1e30f;
      for (int ni = 0; ni < 5; ni++) {
        int c = ni * 16 + lo;
        float v = s[mi][ni][j] * SC;
        pb[ni] = v;
        if (c < 77) mb = fmaxf(mb, v);
      }
      mb = fmaxf(mb, __shfl_xor(mb, 1, 64));
      mb = fmaxf(mb, __shfl_xor(mb, 2, 64));
      mb = fmaxf(mb, __shfl_xor(mb, 4, 64));
      mb = fmaxf(mb, __shfl_xor(mb, 8, 64));
      float sb = 0.f;
      for (int ni = 0; ni < 5; ni++) {
        int c = ni * 16 + lo;
        float p = (c < 77) ? exp2f(pb[ni] - mb) : 0.f;
        pb[ni] = p; sb += p;
      }
      sb += __shfl_xor(sb, 1, 64); sb += __shfl_xor(sb, 2, 64);
      sb += __shfl_xor(sb, 4, 64); sb += __shfl_xor(sb, 8, 64);
      float rb = 1.0f / sb;
      float vip = s[mi][5][j] * SC;
      bool val = lo < 4;
      float mip = val ? vip : -1e30f;
      mip = fmaxf(mip, __shfl_xor(mip, 1, 64));
      mip = fmaxf(mip, __shfl_xor(mip, 2, 64));
      mip = fmaxf(mip, __shfl_xor(mip, 4, 64));
      mip = fmaxf(mip, __shfl_xor(mip, 8, 64));
      float pi = val ? exp2f(vip - mip) : 0.f;
      float si = pi;
      si += __shfl_xor(si, 1, 64); si += __shfl_xor(si, 2, 64);
      si += __shfl_xor(si, 4, 64); si += __shfl_xor(si, 8, 64);
      float ri = 1.0f / si;
      int row = mi * 16 + hi * 4 + j;
      ushort* pr = &P[w][row * 104];
      for (int ni = 0; ni < 5; ni++) pr[ni * 16 + lo] = f2b(pb[ni] * rb);
      pr[80 + lo] = f2b(pi * ri);
    }
  __syncthreads();
  f32x4 o[2][4];
  for (int i = 0; i < 2; i++) for (int j = 0; j < 4; j++) o[i][j] = zf;
  const ushort* Vb = Vt + (size_t)bh * 64 * 96;
  for (int kk = 0; kk < 3; kk++) {
    short8 pf[2];
    for (int mi = 0; mi < 2; mi++)
      pf[mi] = *reinterpret_cast<const short8*>(&P[w][(mi * 16 + lo) * 104 + kk * 32 + hi * 8]);
    for (int dn = 0; dn < 4; dn++) {
      short8 vf = *reinterpret_cast<const short8*>(Vb + (dn * 16 + lo) * 96 + kk * 32 + hi * 8);
      for (int mi = 0; mi < 2; mi++)
        o[mi][dn] = __builtin_amdgcn_mfma_f32_16x16x32_bf16(pf[mi], vf, o[mi][dn], 0, 0, 0);
    }
  }
  ushort* Ob = O + ((size_t)b * 4096 + q0 + w * 32) * 1024 + h * 64;
  for (int mi = 0; mi < 2; mi++)
    for (int dn = 0; dn < 4; dn++)
      for (int j = 0; j < 4; j++)
        Ob[(size_t)(mi * 16 + hi * 4 + j) * 1024 + dn * 16 + lo] = f2b(o[mi][dn][j]);
}

// ---------------------------------------------------------------------------
extern "C" void kernel_launch(void* const* d_in, const int* in_sizes, int n_in,
                              void* d_out, int out_size, void* d_ws, size_t ws_size,
                              hipStream_t stream) {
  const float* hs   = (const float*)d_in[0];
  const float* enc  = (const float*)d_in[1];
  const float* Wq   = (const float*)d_in[2];
  const float* Wk   = (const float*)d_in[3];
  const float* Wv   = (const float*)d_in[4];
  const float* Wkip = (const float*)d_in[5];
  const float* Wvip = (const float*)d_in[6];
  const float* Wo   = (const float*)d_in[7];
  const float* bo   = (const float*)d_in[8];
  const float* lnw  = (const float*)d_in[9];
  const float* lnb  = (const float*)d_in[10];
  float* out = (float*)d_out;
  // d_out (128 MB) doubles as scratch before the final GEMM overwrites it:
  ushort* Qbuf  = (ushort*)d_out;                          // bf16 Q, first 64MB
  ushort* hs_bf = (ushort*)d_out + (size_t)32768 * 1024;   // bf16 hs, second 64MB

  ushort* p = (ushort*)d_ws;
  ushort* attn    = p; p += (size_t)32768 * 1024;
  ushort* wq_bf   = p; p += (size_t)1024 * 1024;
  ushort* wo_bf   = p; p += (size_t)1024 * 1024;
  ushort* wk_bf   = p; p += (size_t)1024 * 768;
  ushort* wkip_bf = p; p += (size_t)1024 * 768;
  ushort* wv_bf   = p; p += (size_t)1024 * 768;
  ushort* wvip_bf = p; p += (size_t)1024 * 768;
  ushort* xn      = p; p += (size_t)8 * 96 * 768;
  ushort* kall    = p; p += (size_t)8 * 16 * 96 * 64;
  ushort* vtall   = p; p += (size_t)8 * 16 * 96 * 64;

  CvtArgs ca;
  ca.src[0] = Wq;   ca.dst[0] = wq_bf;   ca.n4[0] = 262144;
  ca.src[1] = Wo;   ca.dst[1] = wo_bf;   ca.n4[1] = 262144;
  ca.src[2] = Wk;   ca.dst[2] = wk_bf;   ca.n4[2] = 196608;
  ca.src[3] = Wkip; ca.dst[3] = wkip_bf; ca.n4[3] = 196608;
  ca.src[4] = Wv;   ca.dst[4] = wv_bf;   ca.n4[4] = 196608;
  ca.src[5] = Wvip; ca.dst[5] = wvip_bf; ca.n4[5] = 196608;
  k_cvt_all<<<dim3(1024, 6), 256, 0, stream>>>(ca);
  k_cvt_hs<<<16384, 256, 0, stream>>>(hs, hs_bf, 4194304);
  k_build_xn<<<dim3(96, 8), 256, 0, stream>>>(enc, lnw, lnb, xn);
  k_kv<<<dim3(4, 8), 256, 0, stream>>>(xn, wk_bf, wkip_bf, kall, 0);
  k_kv<<<dim3(4, 8), 256, 0, stream>>>(xn, wv_bf, wvip_bf, vtall, 1);
  k_gemm8<false><<<512, 512, 0, stream>>>(hs_bf, wq_bf, nullptr, (void*)Qbuf);
  k_attn<<<dim3(32, 128), 256, 0, stream>>>(Qbuf, kall, vtall, attn);
  k_gemm8<true><<<512, 512, 0, stream>>>(attn, wo_bf, bo, (void*)out);
}